// Round 1
// baseline (521.065 us; speedup 1.0000x reference)
//
#include <hip/hip_runtime.h>
#include <math.h>

#define S_NODES 255
#define B_TREES 256
#define F_IN 64
#define H_DIM 128
#define N_NODES (B_TREES * S_NODES)

__device__ __forceinline__ float sigmoidf_(float x) {
    return 1.0f / (1.0f + expf(-x));
}

// One thread-group of 128 threads handles G nodes; thread j owns H-column j.
// Block = 256 threads = 2 groups.
template <bool LEAF, int G>
__global__ __launch_bounds__(256) void tree_level_kernel(
    const float* __restrict__ feat,
    const float* __restrict__ W_iou, const float* __restrict__ b_iou,
    const float* __restrict__ U_iou,
    const float* __restrict__ W_f, const float* __restrict__ b_f,
    const float* __restrict__ U_f,
    float* __restrict__ h, float* __restrict__ c,
    int Lstart, int Lbits)
{
    const int j = threadIdx.x & 127;
    const int grp = threadIdx.x >> 7;
    const int nodeBase = (blockIdx.x * 2 + grp) * G;

    __shared__ float feat_s[2][G][F_IN];
    __shared__ float hl_s[2][G][H_DIM];
    __shared__ float hr_s[2][G][H_DIM];
    __shared__ float hs_s[2][G][H_DIM];

    int nglob[G];
    float clj[G], crj[G];

    #pragma unroll
    for (int g = 0; g < G; ++g) {
        int idx = nodeBase + g;
        int tree = idx >> Lbits;
        int local = Lstart + (idx & ((1 << Lbits) - 1));
        int n = tree * S_NODES + local;
        nglob[g] = n;
        if (j < F_IN) feat_s[grp][g][j] = feat[n * F_IN + j];
        if (!LEAF) {
            int gl = tree * S_NODES + 2 * local + 1;
            int gr = gl + 1;
            float hlv = h[gl * H_DIM + j];
            float hrv = h[gr * H_DIM + j];
            hl_s[grp][g][j] = hlv;
            hr_s[grp][g][j] = hrv;
            hs_s[grp][g][j] = hlv + hrv;
            clj[g] = c[gl * H_DIM + j];
            crj[g] = c[gr * H_DIM + j];
        } else {
            clj[g] = 0.f; crj[g] = 0.f;
        }
    }
    __syncthreads();

    float acc_i[G], acc_o[G], acc_u[G], acc_f[G], acc_fl[G], acc_fr[G];
    {
        float bi = b_iou[j], bo = b_iou[128 + j], bu = b_iou[256 + j];
        float bf = LEAF ? 0.f : b_f[j];
        #pragma unroll
        for (int g = 0; g < G; ++g) {
            acc_i[g] = bi; acc_o[g] = bo; acc_u[g] = bu;
            acc_f[g] = bf; acc_fl[g] = 0.f; acc_fr[g] = 0.f;
        }
    }

    // feat @ [W_iou | W_f]
    #pragma unroll 4
    for (int k = 0; k < F_IN; ++k) {
        float wi = W_iou[k * 384 + j];
        float wo = W_iou[k * 384 + 128 + j];
        float wu = W_iou[k * 384 + 256 + j];
        float wf = LEAF ? 0.f : W_f[k * H_DIM + j];
        #pragma unroll
        for (int g = 0; g < G; ++g) {
            float fv = feat_s[grp][g][k];
            acc_i[g] = fmaf(fv, wi, acc_i[g]);
            acc_o[g] = fmaf(fv, wo, acc_o[g]);
            acc_u[g] = fmaf(fv, wu, acc_u[g]);
            if (!LEAF) acc_f[g] = fmaf(fv, wf, acc_f[g]);
        }
    }

    if (!LEAF) {
        // h_sum @ U_iou, h_left/right @ U_f
        #pragma unroll 4
        for (int k = 0; k < H_DIM; ++k) {
            float ui = U_iou[k * 384 + j];
            float uo = U_iou[k * 384 + 128 + j];
            float uu = U_iou[k * 384 + 256 + j];
            float uf = U_f[k * H_DIM + j];
            #pragma unroll
            for (int g = 0; g < G; ++g) {
                float hs = hs_s[grp][g][k];
                float hl = hl_s[grp][g][k];
                float hr = hr_s[grp][g][k];
                acc_i[g]  = fmaf(hs, ui, acc_i[g]);
                acc_o[g]  = fmaf(hs, uo, acc_o[g]);
                acc_u[g]  = fmaf(hs, uu, acc_u[g]);
                acc_fl[g] = fmaf(hl, uf, acc_fl[g]);
                acc_fr[g] = fmaf(hr, uf, acc_fr[g]);
            }
        }
    }

    #pragma unroll
    for (int g = 0; g < G; ++g) {
        float cn = sigmoidf_(acc_i[g]) * tanhf(acc_u[g]);
        if (!LEAF) {
            float fl = sigmoidf_(acc_f[g] + acc_fl[g]);
            float fr = sigmoidf_(acc_f[g] + acc_fr[g]);
            cn += fl * clj[g] + fr * crj[g];
        }
        float hn = sigmoidf_(acc_o[g]) * tanhf(cn);
        int n = nglob[g];
        h[n * H_DIM + j] = hn;
        c[n * H_DIM + j] = cn;
    }
}

__global__ __launch_bounds__(128) void readout_kernel(
    const float* __restrict__ h,
    const float* __restrict__ lin1_w, const float* __restrict__ lin1_b,
    const float* __restrict__ lin2_w, const float* __restrict__ lin2_b,
    const float* __restrict__ lin_w, const float* __restrict__ lin_b,
    float* __restrict__ out)
{
    const int b = blockIdx.x;
    const int j = threadIdx.x;
    const float* hb = h + (size_t)b * S_NODES * H_DIM;

    float s = 0.f;
    for (int n = 0; n < S_NODES; ++n) s += hb[n * H_DIM + j];
    float x = fmaxf(s * (1.0f / (float)S_NODES), 0.f);

    __shared__ float xs[H_DIM];
    __shared__ float ys[H_DIM];
    __shared__ float red[2];

    xs[j] = x;
    __syncthreads();
    float a = lin1_b[j];
    #pragma unroll 4
    for (int k = 0; k < H_DIM; ++k) a = fmaf(xs[k], lin1_w[k * H_DIM + j], a);
    a = fmaxf(a, 0.f);
    ys[j] = a;
    __syncthreads();
    float z = lin2_b[j];
    #pragma unroll 4
    for (int k = 0; k < H_DIM; ++k) z = fmaf(ys[k], lin2_w[k * H_DIM + j], z);
    z = fmaxf(z, 0.f);

    float t = z * lin_w[j];
    #pragma unroll
    for (int off = 32; off > 0; off >>= 1) t += __shfl_down(t, off, 64);
    if ((j & 63) == 0) red[j >> 6] = t;
    __syncthreads();
    if (j == 0) out[b] = red[0] + red[1] + lin_b[0];
}

extern "C" void kernel_launch(void* const* d_in, const int* in_sizes, int n_in,
                              void* d_out, int out_size, void* d_ws, size_t ws_size,
                              hipStream_t stream)
{
    const float* feat   = (const float*)d_in[0];
    const float* W_iou  = (const float*)d_in[1];
    const float* b_iou  = (const float*)d_in[2];
    const float* U_iou  = (const float*)d_in[3];
    const float* W_f    = (const float*)d_in[4];
    const float* b_f    = (const float*)d_in[5];
    const float* U_f    = (const float*)d_in[6];
    const float* lin1_w = (const float*)d_in[7];
    const float* lin1_b = (const float*)d_in[8];
    const float* lin2_w = (const float*)d_in[9];
    const float* lin2_b = (const float*)d_in[10];
    const float* lin_w  = (const float*)d_in[11];
    const float* lin_b  = (const float*)d_in[12];
    float* out = (float*)d_out;

    float* h = (float*)d_ws;
    float* c = h + (size_t)N_NODES * H_DIM;

    constexpr int G = 8;

    // lvl = 0: leaves (heap level 7, locals 127..254), 128 per tree
    tree_level_kernel<true, G><<<(B_TREES * 128) / (2 * G), 256, 0, stream>>>(
        feat, W_iou, b_iou, U_iou, W_f, b_f, U_f, h, c, 127, 7);

    // lvl = 1..7: heap level L = 7 - lvl, 2^L parents per tree
    for (int lvl = 1; lvl < 8; ++lvl) {
        int L = 7 - lvl;
        int Lstart = (1 << L) - 1;
        int total = B_TREES << L;
        tree_level_kernel<false, G><<<total / (2 * G), 256, 0, stream>>>(
            feat, W_iou, b_iou, U_iou, W_f, b_f, U_f, h, c, Lstart, L);
    }

    readout_kernel<<<B_TREES, 128, 0, stream>>>(
        h, lin1_w, lin1_b, lin2_w, lin2_b, lin_w, lin_b, out);
}

// Round 2
// 355.424 us; speedup vs baseline: 1.4660x; 1.4660x over previous
//
#include <hip/hip_runtime.h>
#include <math.h>

#define S_NODES 255
#define B_TREES 256
#define F_IN 64
#define H_DIM 128

__device__ __forceinline__ float fsig(float x) {
    // 1/(1+e^-x) via hardware exp2 + rcp; rel err ~1e-6
    float e = __expf(-x);
    return __builtin_amdgcn_rcpf(1.0f + e);
}
__device__ __forceinline__ float ftanh_(float x) {
    x = fminf(fmaxf(x, -15.0f), 15.0f);   // avoid inf/inf
    float e = __expf(2.0f * x);
    return (e - 1.0f) * __builtin_amdgcn_rcpf(e + 1.0f);
}

// One thread-group of 128 threads handles G nodes; thread j owns H-column j.
// Block = 256 threads = 2 groups.
template <bool LEAF, int G>
__global__ __launch_bounds__(256) void tree_level_kernel(
    const float* __restrict__ feat,
    const float* __restrict__ W_iou, const float* __restrict__ b_iou,
    const float* __restrict__ U_iou,
    const float* __restrict__ W_f, const float* __restrict__ b_f,
    const float* __restrict__ U_f,
    float* __restrict__ h, float* __restrict__ c,
    int Lstart, int Lbits)
{
    const int j = threadIdx.x & 127;
    const int grp = threadIdx.x >> 7;
    const int nodeBase = (blockIdx.x * 2 + grp) * G;

    __shared__ float feat_s[2][G][F_IN];
    __shared__ float hl_s[LEAF ? 1 : 2][LEAF ? 1 : G][LEAF ? 1 : H_DIM];
    __shared__ float hr_s[LEAF ? 1 : 2][LEAF ? 1 : G][LEAF ? 1 : H_DIM];

    // ---- stage children h and feat ----
    #pragma unroll
    for (int g = 0; g < G; ++g) {
        int idx = nodeBase + g;
        int tree = idx >> Lbits;
        int local = Lstart + (idx & ((1 << Lbits) - 1));
        int n = tree * S_NODES + local;
        if (j < F_IN) feat_s[grp][g][j] = feat[(size_t)n * F_IN + j];
        if constexpr (!LEAF) {
            int gl = tree * S_NODES + 2 * local + 1;
            hl_s[grp][g][j] = h[(size_t)gl * H_DIM + j];
            hr_s[grp][g][j] = h[(size_t)(gl + 1) * H_DIM + j];
        }
    }
    __syncthreads();

    float acc_i[G], acc_o[G], acc_u[G], acc_f[G], acc_fl[G], acc_fr[G];
    {
        float bi = b_iou[j], bo = b_iou[128 + j], bu = b_iou[256 + j];
        float bf = LEAF ? 0.f : b_f[j];
        #pragma unroll
        for (int g = 0; g < G; ++g) {
            acc_i[g] = bi; acc_o[g] = bo; acc_u[g] = bu;
            acc_f[g] = bf; acc_fl[g] = 0.f; acc_fr[g] = 0.f;
        }
    }

    // ---- feat @ [W_iou | W_f], k unrolled by 4, float4 LDS reads ----
    #pragma unroll 2
    for (int k4 = 0; k4 < F_IN; k4 += 4) {
        float wi[4], wo[4], wu[4], wf[4];
        #pragma unroll
        for (int t = 0; t < 4; ++t) {
            const float* wr = W_iou + (size_t)(k4 + t) * 384;
            wi[t] = wr[j]; wo[t] = wr[128 + j]; wu[t] = wr[256 + j];
            if constexpr (!LEAF) wf[t] = W_f[(size_t)(k4 + t) * H_DIM + j];
            else wf[t] = 0.f;
        }
        #pragma unroll
        for (int g = 0; g < G; ++g) {
            float4 f4 = *reinterpret_cast<const float4*>(&feat_s[grp][g][k4]);
            float fv[4] = {f4.x, f4.y, f4.z, f4.w};
            #pragma unroll
            for (int t = 0; t < 4; ++t) {
                acc_i[g] = fmaf(fv[t], wi[t], acc_i[g]);
                acc_o[g] = fmaf(fv[t], wo[t], acc_o[g]);
                acc_u[g] = fmaf(fv[t], wu[t], acc_u[g]);
                if constexpr (!LEAF) acc_f[g] = fmaf(fv[t], wf[t], acc_f[g]);
            }
        }
    }

    // ---- h_sum @ U_iou, h_left/right @ U_f ----
    if constexpr (!LEAF) {
        #pragma unroll 2
        for (int k4 = 0; k4 < H_DIM; k4 += 4) {
            float ui[4], uo[4], uu[4], uf[4];
            #pragma unroll
            for (int t = 0; t < 4; ++t) {
                const float* ur = U_iou + (size_t)(k4 + t) * 384;
                ui[t] = ur[j]; uo[t] = ur[128 + j]; uu[t] = ur[256 + j];
                uf[t] = U_f[(size_t)(k4 + t) * H_DIM + j];
            }
            #pragma unroll
            for (int g = 0; g < G; ++g) {
                float4 hl4 = *reinterpret_cast<const float4*>(&hl_s[grp][g][k4]);
                float4 hr4 = *reinterpret_cast<const float4*>(&hr_s[grp][g][k4]);
                float hlv[4] = {hl4.x, hl4.y, hl4.z, hl4.w};
                float hrv[4] = {hr4.x, hr4.y, hr4.z, hr4.w};
                #pragma unroll
                for (int t = 0; t < 4; ++t) {
                    float hsv = hlv[t] + hrv[t];
                    acc_i[g]  = fmaf(hsv, ui[t], acc_i[g]);
                    acc_o[g]  = fmaf(hsv, uo[t], acc_o[g]);
                    acc_u[g]  = fmaf(hsv, uu[t], acc_u[g]);
                    acc_fl[g] = fmaf(hlv[t], uf[t], acc_fl[g]);
                    acc_fr[g] = fmaf(hrv[t], uf[t], acc_fr[g]);
                }
            }
        }
    }

    // ---- epilogue: load c of children late (keeps regs low in main loop) ----
    float cl[G], cr[G];
    if constexpr (!LEAF) {
        #pragma unroll
        for (int g = 0; g < G; ++g) {
            int idx = nodeBase + g;
            int tree = idx >> Lbits;
            int local = Lstart + (idx & ((1 << Lbits) - 1));
            int gl = tree * S_NODES + 2 * local + 1;
            cl[g] = c[(size_t)gl * H_DIM + j];
            cr[g] = c[(size_t)(gl + 1) * H_DIM + j];
        }
    }
    #pragma unroll
    for (int g = 0; g < G; ++g) {
        int idx = nodeBase + g;
        int tree = idx >> Lbits;
        int local = Lstart + (idx & ((1 << Lbits) - 1));
        int n = tree * S_NODES + local;
        float cn = fsig(acc_i[g]) * ftanh_(acc_u[g]);
        if constexpr (!LEAF) {
            float fl = fsig(acc_f[g] + acc_fl[g]);
            float fr = fsig(acc_f[g] + acc_fr[g]);
            cn = fmaf(fl, cl[g], fmaf(fr, cr[g], cn));
        }
        float hn = fsig(acc_o[g]) * ftanh_(cn);
        h[(size_t)n * H_DIM + j] = hn;
        c[(size_t)n * H_DIM + j] = cn;
    }
}

__global__ __launch_bounds__(256) void readout_kernel(
    const float* __restrict__ h,
    const float* __restrict__ lin1_w, const float* __restrict__ lin1_b,
    const float* __restrict__ lin2_w, const float* __restrict__ lin2_b,
    const float* __restrict__ lin_w, const float* __restrict__ lin_b,
    float* __restrict__ out)
{
    const int b = blockIdx.x;
    const int j = threadIdx.x & 127;
    const int half = threadIdx.x >> 7;
    const float* hb = h + (size_t)b * S_NODES * H_DIM;

    float s = 0.f;
    #pragma unroll 4
    for (int n = half; n < S_NODES; n += 2) s += hb[n * H_DIM + j];

    __shared__ float part[2][H_DIM];
    __shared__ float xs[H_DIM];
    __shared__ float ys[H_DIM];
    __shared__ float red[2];

    part[half][j] = s;
    __syncthreads();
    if (half == 0) {
        xs[j] = fmaxf((part[0][j] + part[1][j]) * (1.0f / 255.0f), 0.f);
    }
    __syncthreads();
    if (half == 0) {
        float a = lin1_b[j];
        #pragma unroll 4
        for (int k = 0; k < H_DIM; ++k) a = fmaf(xs[k], lin1_w[k * H_DIM + j], a);
        ys[j] = fmaxf(a, 0.f);
    }
    __syncthreads();
    if (half == 0) {
        float z = lin2_b[j];
        #pragma unroll 4
        for (int k = 0; k < H_DIM; ++k) z = fmaf(ys[k], lin2_w[k * H_DIM + j], z);
        z = fmaxf(z, 0.f);
        float t = z * lin_w[j];
        #pragma unroll
        for (int off = 32; off > 0; off >>= 1) t += __shfl_down(t, off, 64);
        if ((j & 63) == 0) red[j >> 6] = t;
    }
    __syncthreads();
    if (threadIdx.x == 0) out[b] = red[0] + red[1] + lin_b[0];
}

extern "C" void kernel_launch(void* const* d_in, const int* in_sizes, int n_in,
                              void* d_out, int out_size, void* d_ws, size_t ws_size,
                              hipStream_t stream)
{
    const float* feat   = (const float*)d_in[0];
    const float* W_iou  = (const float*)d_in[1];
    const float* b_iou  = (const float*)d_in[2];
    const float* U_iou  = (const float*)d_in[3];
    const float* W_f    = (const float*)d_in[4];
    const float* b_f    = (const float*)d_in[5];
    const float* U_f    = (const float*)d_in[6];
    const float* lin1_w = (const float*)d_in[7];
    const float* lin1_b = (const float*)d_in[8];
    const float* lin2_w = (const float*)d_in[9];
    const float* lin2_b = (const float*)d_in[10];
    const float* lin_w  = (const float*)d_in[11];
    const float* lin_b  = (const float*)d_in[12];
    float* out = (float*)d_out;

    float* h = (float*)d_ws;
    float* c = h + (size_t)(B_TREES * S_NODES) * H_DIM;

    // leaves: heap level 7, locals 127..254, 128 per tree -> 32768 nodes
    tree_level_kernel<true, 8><<<(B_TREES * 128) / 16, 256, 0, stream>>>(
        feat, W_iou, b_iou, U_iou, W_f, b_f, U_f, h, c, 127, 7);

    // internal levels, shrinking G to keep >=128 blocks in flight
    // lvl1: heap L=6, 16384 nodes
    tree_level_kernel<false, 8><<<1024, 256, 0, stream>>>(
        feat, W_iou, b_iou, U_iou, W_f, b_f, U_f, h, c, 63, 6);
    // lvl2: L=5, 8192 nodes
    tree_level_kernel<false, 8><<<512, 256, 0, stream>>>(
        feat, W_iou, b_iou, U_iou, W_f, b_f, U_f, h, c, 31, 5);
    // lvl3: L=4, 4096 nodes
    tree_level_kernel<false, 8><<<256, 256, 0, stream>>>(
        feat, W_iou, b_iou, U_iou, W_f, b_f, U_f, h, c, 15, 4);
    // lvl4: L=3, 2048 nodes
    tree_level_kernel<false, 4><<<256, 256, 0, stream>>>(
        feat, W_iou, b_iou, U_iou, W_f, b_f, U_f, h, c, 7, 3);
    // lvl5: L=2, 1024 nodes
    tree_level_kernel<false, 2><<<256, 256, 0, stream>>>(
        feat, W_iou, b_iou, U_iou, W_f, b_f, U_f, h, c, 3, 2);
    // lvl6: L=1, 512 nodes
    tree_level_kernel<false, 1><<<256, 256, 0, stream>>>(
        feat, W_iou, b_iou, U_iou, W_f, b_f, U_f, h, c, 1, 1);
    // lvl7: L=0, 256 nodes (roots)
    tree_level_kernel<false, 1><<<128, 256, 0, stream>>>(
        feat, W_iou, b_iou, U_iou, W_f, b_f, U_f, h, c, 0, 0);

    readout_kernel<<<B_TREES, 256, 0, stream>>>(
        h, lin1_w, lin1_b, lin2_w, lin2_b, lin_w, lin_b, out);
}

// Round 4
// 317.448 us; speedup vs baseline: 1.6414x; 1.1196x over previous
//
#include <hip/hip_runtime.h>
#include <math.h>

#define S_NODES 255
#define B_TREES 256
#define F_IN 64
#define H_DIM 128

__device__ __forceinline__ float fsig(float x) {
    float e = __expf(-x);
    return __builtin_amdgcn_rcpf(1.0f + e);
}
__device__ __forceinline__ float ftanh_(float x) {
    x = fminf(fmaxf(x, -15.0f), 15.0f);
    float e = __expf(2.0f * x);
    return (e - 1.0f) * __builtin_amdgcn_rcpf(e + 1.0f);
}

// ---------------- weight packing ----------------
// Wp[k*128+j] = {W_iou[k][j], W_iou[k][128+j], W_iou[k][256+j], W_f[k][j]}   (k<64)
// Up[k*128+j] = {U_iou[k][j], U_iou[k][128+j], U_iou[k][256+j], U_f[k][j]}   (k<128)
__global__ __launch_bounds__(256) void pack_weights(
    const float* __restrict__ W_iou, const float* __restrict__ W_f,
    const float* __restrict__ U_iou, const float* __restrict__ U_f,
    float4* __restrict__ Wp, float4* __restrict__ Up)
{
    int t = blockIdx.x * 256 + threadIdx.x;
    if (t < F_IN * H_DIM) {
        int k = t >> 7, j = t & 127;
        Wp[t] = make_float4(W_iou[k * 384 + j], W_iou[k * 384 + 128 + j],
                            W_iou[k * 384 + 256 + j], W_f[k * H_DIM + j]);
    } else {
        int t2 = t - F_IN * H_DIM;
        int k = t2 >> 7, j = t2 & 127;
        Up[t2] = make_float4(U_iou[k * 384 + j], U_iou[k * 384 + 128 + j],
                             U_iou[k * 384 + 256 + j], U_f[k * H_DIM + j]);
    }
}

#define ULOOP(KB, KE, HLROW, HRROW)                                             \
    _Pragma("unroll 2")                                                         \
    for (int k4 = (KB); k4 < (KE); k4 += 4) {                                   \
        float4 u0 = Up[(k4 + 0) * H_DIM + j];                                   \
        float4 u1 = Up[(k4 + 1) * H_DIM + j];                                   \
        float4 u2 = Up[(k4 + 2) * H_DIM + j];                                   \
        float4 u3 = Up[(k4 + 3) * H_DIM + j];                                   \
        _Pragma("unroll")                                                       \
        for (int g = 0; g < G; ++g) {                                           \
            float4 hl4 = *reinterpret_cast<const float4*>((HLROW) + k4);        \
            float4 hr4 = *reinterpret_cast<const float4*>((HRROW) + k4);        \
            float hs_;                                                          \
            hs_ = hl4.x + hr4.x;                                                \
            acc_i[g] = fmaf(hs_, u0.x, acc_i[g]);                               \
            acc_o[g] = fmaf(hs_, u0.y, acc_o[g]);                               \
            acc_u[g] = fmaf(hs_, u0.z, acc_u[g]);                               \
            acc_fl[g] = fmaf(hl4.x, u0.w, acc_fl[g]);                           \
            acc_fr[g] = fmaf(hr4.x, u0.w, acc_fr[g]);                           \
            hs_ = hl4.y + hr4.y;                                                \
            acc_i[g] = fmaf(hs_, u1.x, acc_i[g]);                               \
            acc_o[g] = fmaf(hs_, u1.y, acc_o[g]);                               \
            acc_u[g] = fmaf(hs_, u1.z, acc_u[g]);                               \
            acc_fl[g] = fmaf(hl4.y, u1.w, acc_fl[g]);                           \
            acc_fr[g] = fmaf(hr4.y, u1.w, acc_fr[g]);                           \
            hs_ = hl4.z + hr4.z;                                                \
            acc_i[g] = fmaf(hs_, u2.x, acc_i[g]);                               \
            acc_o[g] = fmaf(hs_, u2.y, acc_o[g]);                               \
            acc_u[g] = fmaf(hs_, u2.z, acc_u[g]);                               \
            acc_fl[g] = fmaf(hl4.z, u2.w, acc_fl[g]);                           \
            acc_fr[g] = fmaf(hr4.z, u2.w, acc_fr[g]);                           \
            hs_ = hl4.w + hr4.w;                                                \
            acc_i[g] = fmaf(hs_, u3.x, acc_i[g]);                               \
            acc_o[g] = fmaf(hs_, u3.y, acc_u[g] * 0.f + acc_o[g]);              \
            acc_u[g] = fmaf(hs_, u3.z, acc_u[g]);                               \
            acc_fl[g] = fmaf(hl4.w, u3.w, acc_fl[g]);                           \
            acc_fr[g] = fmaf(hr4.w, u3.w, acc_fr[g]);                           \
        }                                                                       \
    }

// W-loop: feat @ {W_i,W_o,W_u[,W_f]}
#define WLOOP(FS, WITH_F)                                                       \
    _Pragma("unroll 2")                                                         \
    for (int k4 = 0; k4 < F_IN; k4 += 4) {                                      \
        float4 w0 = Wp[(k4 + 0) * H_DIM + j];                                   \
        float4 w1 = Wp[(k4 + 1) * H_DIM + j];                                   \
        float4 w2 = Wp[(k4 + 2) * H_DIM + j];                                   \
        float4 w3 = Wp[(k4 + 3) * H_DIM + j];                                   \
        _Pragma("unroll")                                                       \
        for (int g = 0; g < G; ++g) {                                           \
            float4 f4 = *reinterpret_cast<const float4*>((FS) + g * F_IN + k4); \
            acc_i[g] = fmaf(f4.x, w0.x, acc_i[g]);                              \
            acc_o[g] = fmaf(f4.x, w0.y, acc_o[g]);                              \
            acc_u[g] = fmaf(f4.x, w0.z, acc_u[g]);                              \
            if (WITH_F) acc_f[g] = fmaf(f4.x, w0.w, acc_f[g]);                  \
            acc_i[g] = fmaf(f4.y, w1.x, acc_i[g]);                              \
            acc_o[g] = fmaf(f4.y, w1.y, acc_o[g]);                              \
            acc_u[g] = fmaf(f4.y, w1.z, acc_u[g]);                              \
            if (WITH_F) acc_f[g] = fmaf(f4.y, w1.w, acc_f[g]);                  \
            acc_i[g] = fmaf(f4.z, w2.x, acc_i[g]);                              \
            acc_o[g] = fmaf(f4.z, w2.y, acc_o[g]);                              \
            acc_u[g] = fmaf(f4.z, w2.z, acc_u[g]);                              \
            if (WITH_F) acc_f[g] = fmaf(f4.z, w2.w, acc_f[g]);                  \
            acc_i[g] = fmaf(f4.w, w3.x, acc_i[g]);                              \
            acc_o[g] = fmaf(f4.w, w3.y, acc_o[g]);                              \
            acc_u[g] = fmaf(f4.w, w3.z, acc_u[g]);                              \
            if (WITH_F) acc_f[g] = fmaf(f4.w, w3.w, acc_f[g]);                  \
        }                                                                       \
    }

// ---------------- leaves: iou only ----------------
template <int G>
__global__ __launch_bounds__(256) void tree_leaf_kernel(
    const float* __restrict__ feat, const float4* __restrict__ Wp,
    const float* __restrict__ b_iou,
    float* __restrict__ h, float* __restrict__ c)
{
    const int tid = threadIdx.x;
    const int j = tid & 127;
    const int grp = tid >> 7;
    const int nodeBase = blockIdx.x * 2 * G;

    __shared__ float feat_s[2 * G * F_IN];
    for (int idx = tid; idx < 2 * G * F_IN; idx += 256) {
        int gg = idx >> 6, kk = idx & 63;
        int nidx = nodeBase + gg;
        int tree = nidx >> 7;
        int local = 127 + (nidx & 127);
        feat_s[idx] = feat[(size_t)(tree * S_NODES + local) * F_IN + kk];
    }
    __syncthreads();

    float acc_i[G], acc_o[G], acc_u[G], acc_f[G];
    {
        float bi = b_iou[j], bo = b_iou[128 + j], bu = b_iou[256 + j];
        #pragma unroll
        for (int g = 0; g < G; ++g) { acc_i[g] = bi; acc_o[g] = bo; acc_u[g] = bu; acc_f[g] = 0.f; }
    }
    const float* fs = feat_s + grp * G * F_IN;
    WLOOP(fs, false)

    #pragma unroll
    for (int g = 0; g < G; ++g) {
        int nidx = nodeBase + grp * G + g;
        int tree = nidx >> 7;
        int local = 127 + (nidx & 127);
        size_t n = (size_t)(tree * S_NODES + local);
        float cn = fsig(acc_i[g]) * ftanh_(acc_u[g]);
        float hn = fsig(acc_o[g]) * ftanh_(cn);
        h[n * H_DIM + j] = hn;
        c[n * H_DIM + j] = cn;
    }
}

// ---------------- internal levels with split-K across the 2 groups ----------------
// grp0: W-part + U rows [0,KS); grp1: U rows [KS,128). LDS-reduce, grp0 epilogue.
template <int G, int KS>
__global__ __launch_bounds__(256) void tree_level_ks(
    const float* __restrict__ feat, const float4* __restrict__ Wp,
    const float* __restrict__ b_iou, const float4* __restrict__ Up,
    const float* __restrict__ b_f,
    float* __restrict__ h, float* __restrict__ c,
    int Lstart, int Lbits)
{
    const int tid = threadIdx.x;
    const int j = tid & 127;
    const int grp = tid >> 7;
    const int nodeBase = blockIdx.x * G;

    __shared__ float smem[5 * G * H_DIM];          // 20 KB for G=8
    float* feat_s = smem;                          // [G][64]
    float* hl_s = smem + G * F_IN;                 // [G][128]
    float* hr_s = hl_s + G * H_DIM;                // [G][128]

    for (int idx = tid; idx < G * F_IN; idx += 256) {
        int g = idx >> 6, kk = idx & 63;
        int nidx = nodeBase + g;
        int tree = nidx >> Lbits;
        int local = Lstart + (nidx & ((1 << Lbits) - 1));
        feat_s[idx] = feat[(size_t)(tree * S_NODES + local) * F_IN + kk];
    }
    for (int idx = tid; idx < G * H_DIM; idx += 256) {
        int g = idx >> 7, col = idx & 127;
        int nidx = nodeBase + g;
        int tree = nidx >> Lbits;
        int local = Lstart + (nidx & ((1 << Lbits) - 1));
        int gl = tree * S_NODES + 2 * local + 1;
        hl_s[idx] = h[(size_t)gl * H_DIM + col];
        hr_s[idx] = h[(size_t)(gl + 1) * H_DIM + col];
    }
    __syncthreads();

    float acc_i[G], acc_o[G], acc_u[G], acc_f[G], acc_fl[G], acc_fr[G];
    if (grp == 0) {
        float bi = b_iou[j], bo = b_iou[128 + j], bu = b_iou[256 + j], bf = b_f[j];
        #pragma unroll
        for (int g = 0; g < G; ++g) {
            acc_i[g] = bi; acc_o[g] = bo; acc_u[g] = bu;
            acc_f[g] = bf; acc_fl[g] = 0.f; acc_fr[g] = 0.f;
        }
        WLOOP(feat_s, true)
        ULOOP(0, KS, hl_s + g * H_DIM, hr_s + g * H_DIM)
    } else {
        #pragma unroll
        for (int g = 0; g < G; ++g) {
            acc_i[g] = 0.f; acc_o[g] = 0.f; acc_u[g] = 0.f;
            acc_f[g] = 0.f; acc_fl[g] = 0.f; acc_fr[g] = 0.f;
        }
        ULOOP(KS, H_DIM, hl_s + g * H_DIM, hr_s + g * H_DIM)
    }
    __syncthreads();
    if (grp == 1) {
        #pragma unroll
        for (int g = 0; g < G; ++g) {
            smem[(0 * G + g) * H_DIM + j] = acc_i[g];
            smem[(1 * G + g) * H_DIM + j] = acc_o[g];
            smem[(2 * G + g) * H_DIM + j] = acc_u[g];
            smem[(3 * G + g) * H_DIM + j] = acc_fl[g];
            smem[(4 * G + g) * H_DIM + j] = acc_fr[g];
        }
    }
    __syncthreads();
    if (grp == 0) {
        #pragma unroll
        for (int g = 0; g < G; ++g) {
            acc_i[g]  += smem[(0 * G + g) * H_DIM + j];
            acc_o[g]  += smem[(1 * G + g) * H_DIM + j];
            acc_u[g]  += smem[(2 * G + g) * H_DIM + j];
            acc_fl[g] += smem[(3 * G + g) * H_DIM + j];
            acc_fr[g] += smem[(4 * G + g) * H_DIM + j];
        }
        #pragma unroll
        for (int g = 0; g < G; ++g) {
            int nidx = nodeBase + g;
            int tree = nidx >> Lbits;
            int local = Lstart + (nidx & ((1 << Lbits) - 1));
            int gl = tree * S_NODES + 2 * local + 1;
            float cl = c[(size_t)gl * H_DIM + j];
            float cr = c[(size_t)(gl + 1) * H_DIM + j];
            float cn = fsig(acc_i[g]) * ftanh_(acc_u[g]);
            float fl = fsig(acc_f[g] + acc_fl[g]);
            float fr = fsig(acc_f[g] + acc_fr[g]);
            cn = fmaf(fl, cl, fmaf(fr, cr, cn));
            float hn = fsig(acc_o[g]) * ftanh_(cn);
            size_t n = (size_t)(tree * S_NODES + local);
            h[n * H_DIM + j] = hn;
            c[n * H_DIM + j] = cn;
        }
    }
}

// ---------------- fused top levels (heap L3..L0, locals 0..14), 1 block per tree ----------------
__global__ __launch_bounds__(256) void tree_top_kernel(
    const float* __restrict__ feat, const float4* __restrict__ Wp,
    const float* __restrict__ b_iou, const float4* __restrict__ Up,
    const float* __restrict__ b_f,
    float* __restrict__ h, float* __restrict__ c)
{
    const int tree = blockIdx.x;
    const int tid = threadIdx.x;
    const int j = tid & 127;
    const int grp = tid >> 7;

    __shared__ float h_s[31][H_DIM];
    __shared__ float c_s[31][H_DIM];
    __shared__ float feat_s[2 * 4 * F_IN];
    __shared__ float red5[5][H_DIM];

    // stage children of heap-L3: locals 15..30 (outputs of lvl3 kernel)
    for (int idx = tid; idx < 16 * H_DIM; idx += 256) {
        int loc = 15 + (idx >> 7);
        int col = idx & 127;
        size_t n = (size_t)(tree * S_NODES + loc);
        h_s[loc][col] = h[n * H_DIM + col];
        c_s[loc][col] = c[n * H_DIM + col];
    }
    __syncthreads();

    float bi = b_iou[j], bo = b_iou[128 + j], bu = b_iou[256 + j], bf = b_f[j];

    // --- slots: G nodes per group, locals = base + grp*G + g ---
    #define TOP_SLOT(G_, BASE_)                                                      \
    {                                                                                \
        constexpr int G = G_;                                                        \
        const int base = BASE_;                                                      \
        for (int idx = tid; idx < 2 * G * F_IN; idx += 256) {                        \
            int gg = idx >> 6, kk = idx & 63;                                        \
            int local = base + gg;                                                   \
            feat_s[idx] = feat[(size_t)(tree * S_NODES + local) * F_IN + kk];        \
        }                                                                            \
        __syncthreads();                                                             \
        float acc_i[G], acc_o[G], acc_u[G], acc_f[G], acc_fl[G], acc_fr[G];          \
        _Pragma("unroll")                                                            \
        for (int g = 0; g < G; ++g) {                                                \
            acc_i[g] = bi; acc_o[g] = bo; acc_u[g] = bu;                             \
            acc_f[g] = bf; acc_fl[g] = 0.f; acc_fr[g] = 0.f;                         \
        }                                                                            \
        const float* fs = feat_s + grp * G * F_IN;                                   \
        WLOOP(fs, true)                                                              \
        ULOOP(0, H_DIM, &h_s[2 * (base + grp * G + g) + 1][0],                       \
                         &h_s[2 * (base + grp * G + g) + 2][0])                      \
        _Pragma("unroll")                                                            \
        for (int g = 0; g < G; ++g) {                                                \
            int p = base + grp * G + g;                                              \
            float cl = c_s[2 * p + 1][j];                                            \
            float cr = c_s[2 * p + 2][j];                                            \
            float cn = fsig(acc_i[g]) * ftanh_(acc_u[g]);                            \
            float fl = fsig(acc_f[g] + acc_fl[g]);                                   \
            float fr = fsig(acc_f[g] + acc_fr[g]);                                   \
            cn = fmaf(fl, cl, fmaf(fr, cr, cn));                                     \
            float hn = fsig(acc_o[g]) * ftanh_(cn);                                  \
            h_s[p][j] = hn;                                                          \
            c_s[p][j] = cn;                                                          \
            h[(size_t)(tree * S_NODES + p) * H_DIM + j] = hn;                        \
        }                                                                            \
        __syncthreads();                                                             \
    }

    TOP_SLOT(4, 7)   // heap L3: locals 7..14
    TOP_SLOT(2, 3)   // heap L2: locals 3..6
    TOP_SLOT(1, 1)   // heap L1: locals 1..2
    #undef TOP_SLOT

    // --- root (local 0), split-K across the two groups ---
    {
        constexpr int G = 1;
        constexpr int KS = 44;
        if (tid < F_IN) feat_s[tid] = feat[(size_t)(tree * S_NODES) * F_IN + tid];
        __syncthreads();
        float acc_i[1], acc_o[1], acc_u[1], acc_f[1], acc_fl[1], acc_fr[1];
        if (grp == 0) {
            acc_i[0] = bi; acc_o[0] = bo; acc_u[0] = bu;
            acc_f[0] = bf; acc_fl[0] = 0.f; acc_fr[0] = 0.f;
            WLOOP(feat_s, true)
            ULOOP(0, KS, &h_s[1][0], &h_s[2][0])
        } else {
            acc_i[0] = 0.f; acc_o[0] = 0.f; acc_u[0] = 0.f;
            acc_f[0] = 0.f; acc_fl[0] = 0.f; acc_fr[0] = 0.f;
            ULOOP(KS, H_DIM, &h_s[1][0], &h_s[2][0])
        }
        __syncthreads();
        if (grp == 1) {
            red5[0][j] = acc_i[0];
            red5[1][j] = acc_o[0];
            red5[2][j] = acc_u[0];
            red5[3][j] = acc_fl[0];
            red5[4][j] = acc_fr[0];
        }
        __syncthreads();
        if (grp == 0) {
            acc_i[0] += red5[0][j];
            acc_o[0] += red5[1][j];
            acc_u[0] += red5[2][j];
            acc_fl[0] += red5[3][j];
            acc_fr[0] += red5[4][j];
            float cl = c_s[1][j], cr = c_s[2][j];
            float cn = fsig(acc_i[0]) * ftanh_(acc_u[0]);
            float fl = fsig(acc_f[0] + acc_fl[0]);
            float fr = fsig(acc_f[0] + acc_fr[0]);
            cn = fmaf(fl, cl, fmaf(fr, cr, cn));
            float hn = fsig(acc_o[0]) * ftanh_(cn);
            h[(size_t)(tree * S_NODES) * H_DIM + j] = hn;
        }
    }
}

// ---------------- readout ----------------
__global__ __launch_bounds__(512) void readout_kernel(
    const float* __restrict__ h,
    const float* __restrict__ lin1_w, const float* __restrict__ lin1_b,
    const float* __restrict__ lin2_w, const float* __restrict__ lin2_b,
    const float* __restrict__ lin_w, const float* __restrict__ lin_b,
    float* __restrict__ out)
{
    const int b = blockIdx.x;
    const int tid = threadIdx.x;
    const int q = tid >> 7;
    const int j = tid & 127;
    const float* hb = h + (size_t)b * S_NODES * H_DIM;

    float s = 0.f;
    #pragma unroll 4
    for (int n = q; n < S_NODES; n += 4) s += hb[n * H_DIM + j];

    __shared__ float part[4][H_DIM];
    __shared__ float xs[H_DIM];
    __shared__ float ys[H_DIM];
    __shared__ float red[2];

    part[q][j] = s;
    __syncthreads();
    if (tid < 128) {
        float t = (part[0][j] + part[1][j] + part[2][j] + part[3][j]) * (1.0f / 255.0f);
        xs[j] = fmaxf(t, 0.f);
    }
    __syncthreads();
    if (tid < 128) {
        float a = lin1_b[j];
        #pragma unroll 4
        for (int k = 0; k < H_DIM; ++k) a = fmaf(xs[k], lin1_w[k * H_DIM + j], a);
        ys[j] = fmaxf(a, 0.f);
    }
    __syncthreads();
    if (tid < 128) {
        float z = lin2_b[j];
        #pragma unroll 4
        for (int k = 0; k < H_DIM; ++k) z = fmaf(ys[k], lin2_w[k * H_DIM + j], z);
        z = fmaxf(z, 0.f);
        float t = z * lin_w[j];
        #pragma unroll
        for (int off = 32; off > 0; off >>= 1) t += __shfl_down(t, off, 64);
        if ((j & 63) == 0) red[j >> 6] = t;
    }
    __syncthreads();
    if (tid == 0) out[b] = red[0] + red[1] + lin_b[0];
}

extern "C" void kernel_launch(void* const* d_in, const int* in_sizes, int n_in,
                              void* d_out, int out_size, void* d_ws, size_t ws_size,
                              hipStream_t stream)
{
    const float* feat   = (const float*)d_in[0];
    const float* W_iou  = (const float*)d_in[1];
    const float* b_iou  = (const float*)d_in[2];
    const float* U_iou  = (const float*)d_in[3];
    const float* W_f    = (const float*)d_in[4];
    const float* b_f    = (const float*)d_in[5];
    const float* U_f    = (const float*)d_in[6];
    const float* lin1_w = (const float*)d_in[7];
    const float* lin1_b = (const float*)d_in[8];
    const float* lin2_w = (const float*)d_in[9];
    const float* lin2_b = (const float*)d_in[10];
    const float* lin_w  = (const float*)d_in[11];
    const float* lin_b  = (const float*)d_in[12];
    float* out = (float*)d_out;

    // small fixed allocations first, then the big h/c arrays
    float4* Wp = (float4*)d_ws;                       // 64*128 float4 = 128 KB
    float4* Up = Wp + F_IN * H_DIM;                   // 128*128 float4 = 256 KB
    float* h = (float*)(Up + H_DIM * H_DIM);          // 33.4 MB
    float* c = h + (size_t)(B_TREES * S_NODES) * H_DIM;

    pack_weights<<<(F_IN * H_DIM + H_DIM * H_DIM) / 256, 256, 0, stream>>>(
        W_iou, W_f, U_iou, U_f, Wp, Up);

    // leaves: heap L7, 32768 nodes, 2 groups x G=8 per block
    tree_leaf_kernel<8><<<2048, 256, 0, stream>>>(feat, Wp, b_iou, h, c);

    // internal big levels: split-K blocks of G=8 nodes
    // lvl1: heap L6, 16384 nodes
    tree_level_ks<8, 44><<<2048, 256, 0, stream>>>(feat, Wp, b_iou, Up, b_f, h, c, 63, 6);
    // lvl2: heap L5, 8192 nodes
    tree_level_ks<8, 44><<<1024, 256, 0, stream>>>(feat, Wp, b_iou, Up, b_f, h, c, 31, 5);
    // lvl3: heap L4, 4096 nodes
    tree_level_ks<8, 44><<<512, 256, 0, stream>>>(feat, Wp, b_iou, Up, b_f, h, c, 15, 4);

    // heap L3..L0 fused, one block per tree
    tree_top_kernel<<<B_TREES, 256, 0, stream>>>(feat, Wp, b_iou, Up, b_f, h, c);

    readout_kernel<<<B_TREES, 512, 0, stream>>>(
        h, lin1_w, lin1_b, lin2_w, lin2_b, lin_w, lin_b, out);
}

// Round 5
// 289.372 us; speedup vs baseline: 1.8007x; 1.0970x over previous
//
#include <hip/hip_runtime.h>
#include <hip/hip_bf16.h>
#include <math.h>

#define S_NODES 255
#define B_TREES 256
#define F_IN 64
#define H_DIM 128

typedef __attribute__((ext_vector_type(8))) short short8;
typedef __attribute__((ext_vector_type(4))) float f32x4;

__device__ __forceinline__ float fsig(float x) {
    float e = __expf(-x);
    return __builtin_amdgcn_rcpf(1.0f + e);
}
__device__ __forceinline__ float ftanh_(float x) {
    x = fminf(fmaxf(x, -15.0f), 15.0f);
    float e = __expf(2.0f * x);
    return (e - 1.0f) * __builtin_amdgcn_rcpf(e + 1.0f);
}
__device__ __forceinline__ unsigned short f2bf(float x) {
    union { __hip_bfloat16 b; unsigned short u; } v; v.b = __float2bfloat16(x); return v.u;
}
__device__ __forceinline__ float bf2f(unsigned short u) {
    union { unsigned int w; float f; } v; v.w = ((unsigned int)u) << 16; return v.f;
}
__device__ __forceinline__ unsigned short f2bf_lo(float x) {
    return f2bf(x - bf2f(f2bf(x)));
}

// ---------------- prep: split-bf16 B matrices ----------------
// Btu[n][384]: k''<192 = hi, >=192 = lo.  k<128: U rows; k in [128,192): W' rows
//   cols n<384: U_iou / 0.5*W_iou ; n>=384: U_f / W_f
// Btl[n][128]: k<64 hi, >=64 lo of W_iou (leaf, unhalved), n<384
__global__ __launch_bounds__(256) void prep_bt(
    const float* __restrict__ U_iou, const float* __restrict__ U_f,
    const float* __restrict__ W_iou, const float* __restrict__ W_f,
    unsigned short* __restrict__ Btu, unsigned short* __restrict__ Btl)
{
    int t = blockIdx.x * 256 + threadIdx.x;
    if (t < 512 * 192) {
        int k = t >> 9, n = t & 511;
        float v;
        if (k < 128) v = (n < 384) ? U_iou[k * 384 + n] : U_f[k * 128 + (n - 384)];
        else {
            int kf = k - 128;
            v = (n < 384) ? 0.5f * W_iou[kf * 384 + n] : W_f[kf * 128 + (n - 384)];
        }
        unsigned short hi = f2bf(v);
        Btu[n * 384 + k] = hi;
        Btu[n * 384 + 192 + k] = f2bf(v - bf2f(hi));
    } else {
        int t2 = t - 512 * 192;   // < 384*64
        int k = t2 & 63, n = t2 >> 6;
        float v = W_iou[k * 384 + n];
        unsigned short hi = f2bf(v);
        Btl[n * 128 + k] = hi;
        Btl[n * 128 + 64 + k] = f2bf(v - bf2f(hi));
    }
}

// ---------------- pack fp32 weights for the top kernel ----------------
__global__ __launch_bounds__(256) void pack_weights(
    const float* __restrict__ W_iou, const float* __restrict__ W_f,
    const float* __restrict__ U_iou, const float* __restrict__ U_f,
    float4* __restrict__ Wp, float4* __restrict__ Up)
{
    int t = blockIdx.x * 256 + threadIdx.x;
    if (t < F_IN * H_DIM) {
        int k = t >> 7, j = t & 127;
        Wp[t] = make_float4(W_iou[k * 384 + j], W_iou[k * 384 + 128 + j],
                            W_iou[k * 384 + 256 + j], W_f[k * H_DIM + j]);
    } else {
        int t2 = t - F_IN * H_DIM;
        int k = t2 >> 7, j = t2 & 127;
        Up[t2] = make_float4(U_iou[k * 384 + j], U_iou[k * 384 + 128 + j],
                             U_iou[k * 384 + 256 + j], U_f[k * H_DIM + j]);
    }
}

#define MFMA(a, b, c) __builtin_amdgcn_mfma_f32_16x16x32_bf16(a, b, c, 0, 0, 0)

// ---------------- leaf GEMM: 32 leaves/block, N=384, K=64 split ----------------
__global__ __launch_bounds__(256, 3) void leafgemm(
    const float* __restrict__ feat, const unsigned short* __restrict__ Btl,
    const float* __restrict__ b_iou,
    float* __restrict__ h, float* __restrict__ c_out,
    unsigned short* __restrict__ h2out)
{
    __shared__ __align__(16) char smem[49152];
    char* Alb = smem;            // 32 rows x 256 B
    char* Blb = smem + 8192;     // 384 rows x 64 B
    const int tid = threadIdx.x;
    const int w = tid >> 6, l = tid & 63;
    const int l15 = l & 15, l4 = l >> 4;
    const int NB = blockIdx.x << 5;

    // A stage: 32 rows x 16 chunks (0..7 feat-hi, 8..15 feat-lo)
    #pragma unroll
    for (int i = 0; i < 2; ++i) {
        int slot = tid + (i << 8);
        int row = slot >> 4, ch = slot & 15;
        int leafidx = NB + row;
        int tree = leafidx >> 7;
        int grow = tree * S_NODES + 127 + (leafidx & 127);
        const float* fp = feat + grow * F_IN + ((ch & 7) << 3);
        unsigned int q[4];
        if (ch < 8) {
            #pragma unroll
            for (int e = 0; e < 4; ++e)
                q[e] = (unsigned)f2bf(fp[2*e]) | ((unsigned)f2bf(fp[2*e+1]) << 16);
        } else {
            #pragma unroll
            for (int e = 0; e < 4; ++e)
                q[e] = (unsigned)f2bf_lo(fp[2*e]) | ((unsigned)f2bf_lo(fp[2*e+1]) << 16);
        }
        *(uint4*)(Alb + (row << 8) + (((ch << 4)) ^ ((row & 7) << 4))) = make_uint4(q[0], q[1], q[2], q[3]);
    }

    f32x4 acc[12];
    #pragma unroll
    for (int i = 0; i < 12; ++i) acc[i] = (f32x4){0.f, 0.f, 0.f, 0.f};

    const int cbase = w * 96;
    const int rA0 = l15, rA1 = 16 + l15;
    const int swzA0 = (rA0 & 7) << 4, swzA1 = (rA1 & 7) << 4;

    for (int s = 0; s < 2; ++s) {
        // stage B hi slice
        #pragma unroll
        for (int i = 0; i < 6; ++i) {
            int slot = tid + (i << 8);
            int n = slot >> 2, cc = slot & 3;
            uint4 v = *(const uint4*)((const char*)Btl + (n << 8) + (s << 6) + (cc << 4));
            *(uint4*)(Blb + (n << 6) + (((cc << 4)) ^ (((n >> 2) & 3) << 4))) = v;
        }
        __syncthreads();
        short8 ah0 = *(const short8*)(Alb + (rA0 << 8) + ((((s << 2) + l4) << 4) ^ swzA0));
        short8 ah1 = *(const short8*)(Alb + (rA1 << 8) + ((((s << 2) + l4) << 4) ^ swzA1));
        short8 al0 = *(const short8*)(Alb + (rA0 << 8) + (((8 + (s << 2) + l4) << 4) ^ swzA0));
        short8 al1 = *(const short8*)(Alb + (rA1 << 8) + (((8 + (s << 2) + l4) << 4) ^ swzA1));
        short8 bh[6];
        #pragma unroll
        for (int ct = 0; ct < 6; ++ct) {
            int n = cbase + (ct << 4) + l15;
            bh[ct] = *(const short8*)(Blb + (n << 6) + ((l4 << 4) ^ (((n >> 2) & 3) << 4)));
        }
        #pragma unroll
        for (int ct = 0; ct < 6; ++ct) acc[ct] = MFMA(ah0, bh[ct], acc[ct]);
        #pragma unroll
        for (int ct = 0; ct < 6; ++ct) acc[6 + ct] = MFMA(ah1, bh[ct], acc[6 + ct]);
        #pragma unroll
        for (int ct = 0; ct < 6; ++ct) acc[ct] = MFMA(al0, bh[ct], acc[ct]);
        #pragma unroll
        for (int ct = 0; ct < 6; ++ct) acc[6 + ct] = MFMA(al1, bh[ct], acc[6 + ct]);
        __syncthreads();
        // stage B lo slice
        #pragma unroll
        for (int i = 0; i < 6; ++i) {
            int slot = tid + (i << 8);
            int n = slot >> 2, cc = slot & 3;
            uint4 v = *(const uint4*)((const char*)Btl + (n << 8) + 128 + (s << 6) + (cc << 4));
            *(uint4*)(Blb + (n << 6) + (((cc << 4)) ^ (((n >> 2) & 3) << 4))) = v;
        }
        __syncthreads();
        #pragma unroll
        for (int ct = 0; ct < 6; ++ct) {
            int n = cbase + (ct << 4) + l15;
            short8 bl = *(const short8*)(Blb + (n << 6) + ((l4 << 4) ^ (((n >> 2) & 3) << 4)));
            acc[ct] = MFMA(ah0, bl, acc[ct]);
            acc[6 + ct] = MFMA(ah1, bl, acc[6 + ct]);
        }
        __syncthreads();
    }

    // dump C to LDS: S[32][384]
    float* S = (float*)smem;
    #pragma unroll
    for (int ct = 0; ct < 6; ++ct) {
        int col = cbase + (ct << 4) + l15;
        #pragma unroll
        for (int rr = 0; rr < 4; ++rr) {
            S[((l4 << 2) + rr) * 384 + col] = acc[ct][rr];
            S[(16 + (l4 << 2) + rr) * 384 + col] = acc[6 + ct][rr];
        }
    }
    __syncthreads();

    // pointwise leaf epilogue
    #pragma unroll
    for (int i = 0; i < 16; ++i) {
        int it = tid + (i << 8);
        int n = it >> 7, j = it & 127;
        int leafidx = NB + n;
        int tree = leafidx >> 7;
        int grow = tree * S_NODES + 127 + (leafidx & 127);
        float iv = S[n * 384 + j] + b_iou[j];
        float ov = S[n * 384 + 128 + j] + b_iou[128 + j];
        float uv = S[n * 384 + 256 + j] + b_iou[256 + j];
        float cn = fsig(iv) * ftanh_(uv);
        float hn = fsig(ov) * ftanh_(cn);
        h[grow * 128 + j] = hn;
        c_out[grow * 128 + j] = cn;
        unsigned short hi = f2bf(hn);
        h2out[grow * 256 + j] = hi;
        h2out[grow * 256 + 128 + j] = f2bf(hn - bf2f(hi));
    }
}

// ---------------- internal-level GEMM: 16 nodes (32 child rows)/block ----------------
// A-row = [h_child(128) | feat_parent(64)] split-bf16; B = Btu. N=512, K=192 split.
__global__ __launch_bounds__(256, 2) void ugemm(
    const float* __restrict__ feat, const unsigned short* __restrict__ h2,
    const float* __restrict__ c_in, const unsigned short* __restrict__ Btu,
    const float* __restrict__ b_iou, const float* __restrict__ b_f,
    float* __restrict__ h, float* __restrict__ c_out,
    unsigned short* __restrict__ h2out,
    int Lstart, int Lbits)
{
    __shared__ __align__(16) char smem[57344];
    char* Alb = smem;            // 32 rows x 768 B
    char* Blb = smem + 24576;    // 512 rows x 64 B
    const int tid = threadIdx.x;
    const int w = tid >> 6, l = tid & 63;
    const int l15 = l & 15, l4 = l >> 4;
    const int NB = blockIdx.x << 4;
    const int mask = (1 << Lbits) - 1;

    // A stage: 32 rows x 48 chunks
    {
        const int row = tid >> 3;
        const int node = NB + (row >> 1);
        const int lr = row & 1;
        const int tree = node >> Lbits;
        const int local = Lstart + (node & mask);
        const int growp = tree * S_NODES + local;
        const int growc = tree * S_NODES + 2 * local + 1 + lr;
        char* arow = Alb + row * 768;
        const int r7 = (row & 7) << 4;
        #pragma unroll
        for (int i = 0; i < 6; ++i) {
            int ch = (tid & 7) + (i << 3);
            uint4 v;
            if (ch < 16) {
                v = *(const uint4*)(h2 + growc * 256 + (ch << 3));
            } else if (ch < 24) {
                const float* fp = feat + growp * F_IN + ((ch & 7) << 3);
                unsigned int q0 = (unsigned)f2bf(fp[0]) | ((unsigned)f2bf(fp[1]) << 16);
                unsigned int q1 = (unsigned)f2bf(fp[2]) | ((unsigned)f2bf(fp[3]) << 16);
                unsigned int q2 = (unsigned)f2bf(fp[4]) | ((unsigned)f2bf(fp[5]) << 16);
                unsigned int q3 = (unsigned)f2bf(fp[6]) | ((unsigned)f2bf(fp[7]) << 16);
                v = make_uint4(q0, q1, q2, q3);
            } else if (ch < 40) {
                v = *(const uint4*)(h2 + growc * 256 + 128 + ((ch - 24) << 3));
            } else {
                const float* fp = feat + growp * F_IN + ((ch & 7) << 3);
                unsigned int q0 = (unsigned)f2bf_lo(fp[0]) | ((unsigned)f2bf_lo(fp[1]) << 16);
                unsigned int q1 = (unsigned)f2bf_lo(fp[2]) | ((unsigned)f2bf_lo(fp[3]) << 16);
                unsigned int q2 = (unsigned)f2bf_lo(fp[4]) | ((unsigned)f2bf_lo(fp[5]) << 16);
                unsigned int q3 = (unsigned)f2bf_lo(fp[6]) | ((unsigned)f2bf_lo(fp[7]) << 16);
                v = make_uint4(q0, q1, q2, q3);
            }
            *(uint4*)(arow + ((ch << 4) ^ r7)) = v;
        }
    }

    f32x4 acc[16];
    #pragma unroll
    for (int i = 0; i < 16; ++i) acc[i] = (f32x4){0.f, 0.f, 0.f, 0.f};

    const int cbase = w << 7;
    const int rA0 = l15, rA1 = 16 + l15;
    const int swzA0 = (rA0 & 7) << 4, swzA1 = (rA1 & 7) << 4;

    for (int s = 0; s < 6; ++s) {
        // stage B hi slice
        #pragma unroll
        for (int nn = 0; nn < 2; ++nn) {
            int n = tid + (nn << 8);
            const char* src = (const char*)Btu + n * 768 + (s << 6);
            char* dst = Blb + (n << 6);
            int sw = ((n >> 2) & 3) << 4;
            #pragma unroll
            for (int cc = 0; cc < 4; ++cc)
                *(uint4*)(dst + ((cc << 4) ^ sw)) = *(const uint4*)(src + (cc << 4));
        }
        __syncthreads();
        short8 ah0 = *(const short8*)(Alb + rA0 * 768 + ((((s << 2) + l4) << 4) ^ swzA0));
        short8 ah1 = *(const short8*)(Alb + rA1 * 768 + ((((s << 2) + l4) << 4) ^ swzA1));
        short8 al0 = *(const short8*)(Alb + rA0 * 768 + (((24 + (s << 2) + l4) << 4) ^ swzA0));
        short8 al1 = *(const short8*)(Alb + rA1 * 768 + (((24 + (s << 2) + l4) << 4) ^ swzA1));
        short8 bh[8];
        #pragma unroll
        for (int ct = 0; ct < 8; ++ct) {
            int n = cbase + (ct << 4) + l15;
            bh[ct] = *(const short8*)(Blb + (n << 6) + ((l4 << 4) ^ (((n >> 2) & 3) << 4)));
        }
        #pragma unroll
        for (int ct = 0; ct < 8; ++ct) acc[ct] = MFMA(ah0, bh[ct], acc[ct]);
        #pragma unroll
        for (int ct = 0; ct < 8; ++ct) acc[8 + ct] = MFMA(ah1, bh[ct], acc[8 + ct]);
        #pragma unroll
        for (int ct = 0; ct < 8; ++ct) acc[ct] = MFMA(al0, bh[ct], acc[ct]);
        #pragma unroll
        for (int ct = 0; ct < 8; ++ct) acc[8 + ct] = MFMA(al1, bh[ct], acc[8 + ct]);
        __syncthreads();
        // stage B lo slice
        #pragma unroll
        for (int nn = 0; nn < 2; ++nn) {
            int n = tid + (nn << 8);
            const char* src = (const char*)Btu + n * 768 + 384 + (s << 6);
            char* dst = Blb + (n << 6);
            int sw = ((n >> 2) & 3) << 4;
            #pragma unroll
            for (int cc = 0; cc < 4; ++cc)
                *(uint4*)(dst + ((cc << 4) ^ sw)) = *(const uint4*)(src + (cc << 4));
        }
        __syncthreads();
        #pragma unroll
        for (int ct = 0; ct < 8; ++ct) {
            int n = cbase + (ct << 4) + l15;
            short8 bl = *(const short8*)(Blb + (n << 6) + ((l4 << 4) ^ (((n >> 2) & 3) << 4)));
            acc[ct] = MFMA(ah0, bl, acc[ct]);
            acc[8 + ct] = MFMA(ah1, bl, acc[8 + ct]);
        }
        __syncthreads();
    }

    // dump: S[16][384] pre-acts (row-pair summed), F[16][2][128] f pre-acts
    float* S = (float*)smem;
    float* F = (float*)(smem + 24576);
    {
        int nb0 = l4 << 1;
        #pragma unroll
        for (int ct = 0; ct < 8; ++ct) {
            int col = cbase + (ct << 4) + l15;
            if (w < 3) {
                S[nb0 * 384 + col]        = acc[ct][0] + acc[ct][1];
                S[(nb0 + 1) * 384 + col]  = acc[ct][2] + acc[ct][3];
                S[(8 + nb0) * 384 + col]      = acc[8 + ct][0] + acc[8 + ct][1];
                S[(8 + nb0 + 1) * 384 + col]  = acc[8 + ct][2] + acc[8 + ct][3];
            } else {
                int fc = col - 384;
                F[(nb0 * 2 + 0) * 128 + fc]       = acc[ct][0];
                F[(nb0 * 2 + 1) * 128 + fc]       = acc[ct][1];
                F[((nb0 + 1) * 2 + 0) * 128 + fc] = acc[ct][2];
                F[((nb0 + 1) * 2 + 1) * 128 + fc] = acc[ct][3];
                F[((8 + nb0) * 2 + 0) * 128 + fc]       = acc[8 + ct][0];
                F[((8 + nb0) * 2 + 1) * 128 + fc]       = acc[8 + ct][1];
                F[((8 + nb0 + 1) * 2 + 0) * 128 + fc]   = acc[8 + ct][2];
                F[((8 + nb0 + 1) * 2 + 1) * 128 + fc]   = acc[8 + ct][3];
            }
        }
    }
    __syncthreads();

    // pointwise epilogue
    #pragma unroll
    for (int i = 0; i < 8; ++i) {
        int it = tid + (i << 8);
        int n = it >> 7, j = it & 127;
        int node = NB + n;
        int tree = node >> Lbits;
        int local = Lstart + (node & mask);
        int gp = tree * S_NODES + local;
        int gl = tree * S_NODES + 2 * local + 1;
        float cl = c_in[gl * 128 + j], cr = c_in[(gl + 1) * 128 + j];
        float iv = S[n * 384 + j] + b_iou[j];
        float ov = S[n * 384 + 128 + j] + b_iou[128 + j];
        float uv = S[n * 384 + 256 + j] + b_iou[256 + j];
        float bfj = b_f[j];
        float fl = fsig(F[(n * 2) * 128 + j] + bfj);
        float fr = fsig(F[(n * 2 + 1) * 128 + j] + bfj);
        float cn = fsig(iv) * ftanh_(uv) + fl * cl + fr * cr;
        float hn = fsig(ov) * ftanh_(cn);
        h[gp * 128 + j] = hn;
        c_out[gp * 128 + j] = cn;
        unsigned short hi = f2bf(hn);
        h2out[gp * 256 + j] = hi;
        h2out[gp * 256 + 128 + j] = f2bf(hn - bf2f(hi));
    }
}

// ---------------- fp32 VALU macros for the top kernel (verified R4) ----------------
#define ULOOP(KB, KE, HLROW, HRROW)                                             \
    _Pragma("unroll 2")                                                         \
    for (int k4 = (KB); k4 < (KE); k4 += 4) {                                   \
        float4 u0 = Up[(k4 + 0) * H_DIM + j];                                   \
        float4 u1 = Up[(k4 + 1) * H_DIM + j];                                   \
        float4 u2 = Up[(k4 + 2) * H_DIM + j];                                   \
        float4 u3 = Up[(k4 + 3) * H_DIM + j];                                   \
        _Pragma("unroll")                                                       \
        for (int g = 0; g < G; ++g) {                                           \
            float4 hl4 = *reinterpret_cast<const float4*>((HLROW) + k4);        \
            float4 hr4 = *reinterpret_cast<const float4*>((HRROW) + k4);        \
            float hs_;                                                          \
            hs_ = hl4.x + hr4.x;                                                \
            acc_i[g] = fmaf(hs_, u0.x, acc_i[g]);                               \
            acc_o[g] = fmaf(hs_, u0.y, acc_o[g]);                               \
            acc_u[g] = fmaf(hs_, u0.z, acc_u[g]);                               \
            acc_fl[g] = fmaf(hl4.x, u0.w, acc_fl[g]);                           \
            acc_fr[g] = fmaf(hr4.x, u0.w, acc_fr[g]);                           \
            hs_ = hl4.y + hr4.y;                                                \
            acc_i[g] = fmaf(hs_, u1.x, acc_i[g]);                               \
            acc_o[g] = fmaf(hs_, u1.y, acc_o[g]);                               \
            acc_u[g] = fmaf(hs_, u1.z, acc_u[g]);                               \
            acc_fl[g] = fmaf(hl4.y, u1.w, acc_fl[g]);                           \
            acc_fr[g] = fmaf(hr4.y, u1.w, acc_fr[g]);                           \
            hs_ = hl4.z + hr4.z;                                                \
            acc_i[g] = fmaf(hs_, u2.x, acc_i[g]);                               \
            acc_o[g] = fmaf(hs_, u2.y, acc_o[g]);                               \
            acc_u[g] = fmaf(hs_, u2.z, acc_u[g]);                               \
            acc_fl[g] = fmaf(hl4.z, u2.w, acc_fl[g]);                           \
            acc_fr[g] = fmaf(hr4.z, u2.w, acc_fr[g]);                           \
            hs_ = hl4.w + hr4.w;                                                \
            acc_i[g] = fmaf(hs_, u3.x, acc_i[g]);                               \
            acc_o[g] = fmaf(hs_, u3.y, acc_o[g]);                               \
            acc_u[g] = fmaf(hs_, u3.z, acc_u[g]);                               \
            acc_fl[g] = fmaf(hl4.w, u3.w, acc_fl[g]);                           \
            acc_fr[g] = fmaf(hr4.w, u3.w, acc_fr[g]);                           \
        }                                                                       \
    }

#define WLOOP(FS, WITH_F)                                                       \
    _Pragma("unroll 2")                                                         \
    for (int k4 = 0; k4 < F_IN; k4 += 4) {                                      \
        float4 w0 = Wp[(k4 + 0) * H_DIM + j];                                   \
        float4 w1 = Wp[(k4 + 1) * H_DIM + j];                                   \
        float4 w2 = Wp[(k4 + 2) * H_DIM + j];                                   \
        float4 w3 = Wp[(k4 + 3) * H_DIM + j];                                   \
        _Pragma("unroll")                                                       \
        for (int g = 0; g < G; ++g) {                                           \
            float4 f4 = *reinterpret_cast<const float4*>((FS) + g * F_IN + k4); \
            acc_i[g] = fmaf(f4.x, w0.x, acc_i[g]);                              \
            acc_o[g] = fmaf(f4.x, w0.y, acc_o[g]);                              \
            acc_u[g] = fmaf(f4.x, w0.z, acc_u[g]);                              \
            if (WITH_F) acc_f[g] = fmaf(f4.x, w0.w, acc_f[g]);                  \
            acc_i[g] = fmaf(f4.y, w1.x, acc_i[g]);                              \
            acc_o[g] = fmaf(f4.y, w1.y, acc_o[g]);                              \
            acc_u[g] = fmaf(f4.y, w1.z, acc_u[g]);                              \
            if (WITH_F) acc_f[g] = fmaf(f4.y, w1.w, acc_f[g]);                  \
            acc_i[g] = fmaf(f4.z, w2.x, acc_i[g]);                              \
            acc_o[g] = fmaf(f4.z, w2.y, acc_o[g]);                              \
            acc_u[g] = fmaf(f4.z, w2.z, acc_u[g]);                              \
            if (WITH_F) acc_f[g] = fmaf(f4.z, w2.w, acc_f[g]);                  \
            acc_i[g] = fmaf(f4.w, w3.x, acc_i[g]);                              \
            acc_o[g] = fmaf(f4.w, w3.y, acc_o[g]);                              \
            acc_u[g] = fmaf(f4.w, w3.z, acc_u[g]);                              \
            if (WITH_F) acc_f[g] = fmaf(f4.w, w3.w, acc_f[g]);                  \
        }                                                                       \
    }

// ---------------- fused top levels (heap L3..L0), 1 block/tree (verified R4) ----------------
__global__ __launch_bounds__(256) void tree_top_kernel(
    const float* __restrict__ feat, const float4* __restrict__ Wp,
    const float* __restrict__ b_iou, const float4* __restrict__ Up,
    const float* __restrict__ b_f,
    float* __restrict__ h, float* __restrict__ c)
{
    const int tree = blockIdx.x;
    const int tid = threadIdx.x;
    const int j = tid & 127;
    const int grp = tid >> 7;

    __shared__ float h_s[31][H_DIM];
    __shared__ float c_s[31][H_DIM];
    __shared__ float feat_s[2 * 4 * F_IN];
    __shared__ float red5[5][H_DIM];

    for (int idx = tid; idx < 16 * H_DIM; idx += 256) {
        int loc = 15 + (idx >> 7);
        int col = idx & 127;
        size_t n = (size_t)(tree * S_NODES + loc);
        h_s[loc][col] = h[n * H_DIM + col];
        c_s[loc][col] = c[n * H_DIM + col];
    }
    __syncthreads();

    float bi = b_iou[j], bo = b_iou[128 + j], bu = b_iou[256 + j], bf = b_f[j];

    #define TOP_SLOT(G_, BASE_)                                                      \
    {                                                                                \
        constexpr int G = G_;                                                        \
        const int base = BASE_;                                                      \
        for (int idx = tid; idx < 2 * G * F_IN; idx += 256) {                        \
            int gg = idx >> 6, kk = idx & 63;                                        \
            int local = base + gg;                                                   \
            feat_s[idx] = feat[(size_t)(tree * S_NODES + local) * F_IN + kk];        \
        }                                                                            \
        __syncthreads();                                                             \
        float acc_i[G], acc_o[G], acc_u[G], acc_f[G], acc_fl[G], acc_fr[G];          \
        _Pragma("unroll")                                                            \
        for (int g = 0; g < G; ++g) {                                                \
            acc_i[g] = bi; acc_o[g] = bo; acc_u[g] = bu;                             \
            acc_f[g] = bf; acc_fl[g] = 0.f; acc_fr[g] = 0.f;                         \
        }                                                                            \
        const float* fs = feat_s + grp * G * F_IN;                                   \
        WLOOP(fs, true)                                                              \
        ULOOP(0, H_DIM, &h_s[2 * (base + grp * G + g) + 1][0],                       \
                         &h_s[2 * (base + grp * G + g) + 2][0])                      \
        _Pragma("unroll")                                                            \
        for (int g = 0; g < G; ++g) {                                                \
            int p = base + grp * G + g;                                              \
            float cl = c_s[2 * p + 1][j];                                            \
            float cr = c_s[2 * p + 2][j];                                            \
            float cn = fsig(acc_i[g]) * ftanh_(acc_u[g]);                            \
            float fl = fsig(acc_f[g] + acc_fl[g]);                                   \
            float fr = fsig(acc_f[g] + acc_fr[g]);                                   \
            cn = fmaf(fl, cl, fmaf(fr, cr, cn));                                     \
            float hn = fsig(acc_o[g]) * ftanh_(cn);                                  \
            h_s[p][j] = hn;                                                          \
            c_s[p][j] = cn;                                                          \
            h[(size_t)(tree * S_NODES + p) * H_DIM + j] = hn;                        \
        }                                                                            \
        __syncthreads();                                                             \
    }

    TOP_SLOT(4, 7)
    TOP_SLOT(2, 3)
    TOP_SLOT(1, 1)
    #undef TOP_SLOT

    {
        constexpr int G = 1;
        constexpr int KS = 44;
        if (tid < F_IN) feat_s[tid] = feat[(size_t)(tree * S_NODES) * F_IN + tid];
        __syncthreads();
        float acc_i[1], acc_o[1], acc_u[1], acc_f[1], acc_fl[1], acc_fr[1];
        if (grp == 0) {
            acc_i[0] = bi; acc_o[0] = bo; acc_u[0] = bu;
            acc_f[0] = bf; acc_fl[0] = 0.f; acc_fr[0] = 0.f;
            WLOOP(feat_s, true)
            ULOOP(0, KS, &h_s[1][0], &h_s[2][0])
        } else {
            acc_i[0] = 0.f; acc_o[0] = 0.f; acc_u[0] = 0.f;
            acc_f[0] = 0.f; acc_fl[0] = 0.f; acc_fr[0] = 0.f;
            ULOOP(KS, H_DIM, &h_s[1][0], &h_s[2][0])
        }
        __syncthreads();
        if (grp == 1) {
            red5[0][j] = acc_i[0];
            red5[1][j] = acc_o[0];
            red5[2][j] = acc_u[0];
            red5[3][j] = acc_fl[0];
            red5[4][j] = acc_fr[0];
        }
        __syncthreads();
        if (grp == 0) {
            acc_i[0] += red5[0][j];
            acc_o[0] += red5[1][j];
            acc_u[0] += red5[2][j];
            acc_fl[0] += red5[3][j];
            acc_fr[0] += red5[4][j];
            float cl = c_s[1][j], cr = c_s[2][j];
            float cn = fsig(acc_i[0]) * ftanh_(acc_u[0]);
            float fl = fsig(acc_f[0] + acc_fl[0]);
            float fr = fsig(acc_f[0] + acc_fr[0]);
            cn = fmaf(fl, cl, fmaf(fr, cr, cn));
            float hn = fsig(acc_o[0]) * ftanh_(cn);
            h[(size_t)(tree * S_NODES) * H_DIM + j] = hn;
        }
    }
}

// ---------------- readout (verified R4) ----------------
__global__ __launch_bounds__(512) void readout_kernel(
    const float* __restrict__ h,
    const float* __restrict__ lin1_w, const float* __restrict__ lin1_b,
    const float* __restrict__ lin2_w, const float* __restrict__ lin2_b,
    const float* __restrict__ lin_w, const float* __restrict__ lin_b,
    float* __restrict__ out)
{
    const int b = blockIdx.x;
    const int tid = threadIdx.x;
    const int q = tid >> 7;
    const int j = tid & 127;
    const float* hb = h + (size_t)b * S_NODES * H_DIM;

    float s = 0.f;
    #pragma unroll 4
    for (int n = q; n < S_NODES; n += 4) s += hb[n * H_DIM + j];

    __shared__ float part[4][H_DIM];
    __shared__ float xs[H_DIM];
    __shared__ float ys[H_DIM];
    __shared__ float red[2];

    part[q][j] = s;
    __syncthreads();
    if (tid < 128) {
        float t = (part[0][j] + part[1][j] + part[2][j] + part[3][j]) * (1.0f / 255.0f);
        xs[j] = fmaxf(t, 0.f);
    }
    __syncthreads();
    if (tid < 128) {
        float a = lin1_b[j];
        #pragma unroll 4
        for (int k = 0; k < H_DIM; ++k) a = fmaf(xs[k], lin1_w[k * H_DIM + j], a);
        ys[j] = fmaxf(a, 0.f);
    }
    __syncthreads();
    if (tid < 128) {
        float z = lin2_b[j];
        #pragma unroll 4
        for (int k = 0; k < H_DIM; ++k) z = fmaf(ys[k], lin2_w[k * H_DIM + j], z);
        z = fmaxf(z, 0.f);
        float t = z * lin_w[j];
        #pragma unroll
        for (int off = 32; off > 0; off >>= 1) t += __shfl_down(t, off, 64);
        if ((j & 63) == 0) red[j >> 6] = t;
    }
    __syncthreads();
    if (tid == 0) out[b] = red[0] + red[1] + lin_b[0];
}

extern "C" void kernel_launch(void* const* d_in, const int* in_sizes, int n_in,
                              void* d_out, int out_size, void* d_ws, size_t ws_size,
                              hipStream_t stream)
{
    const float* feat   = (const float*)d_in[0];
    const float* W_iou  = (const float*)d_in[1];
    const float* b_iou  = (const float*)d_in[2];
    const float* U_iou  = (const float*)d_in[3];
    const float* W_f    = (const float*)d_in[4];
    const float* b_f    = (const float*)d_in[5];
    const float* U_f    = (const float*)d_in[6];
    const float* lin1_w = (const float*)d_in[7];
    const float* lin1_b = (const float*)d_in[8];
    const float* lin2_w = (const float*)d_in[9];
    const float* lin2_b = (const float*)d_in[10];
    const float* lin_w  = (const float*)d_in[11];
    const float* lin_b  = (const float*)d_in[12];
    float* out = (float*)d_out;

    char* wsb = (char*)d_ws;
    float4* Wp = (float4*)wsb;                                   // 128 KB
    float4* Up = (float4*)(wsb + 131072);                        // 256 KB
    unsigned short* Btu = (unsigned short*)(wsb + 393216);       // 384 KB
    unsigned short* Btl = (unsigned short*)(wsb + 786432);       // 96 KB
    float* h  = (float*)(wsb + 884736);                          // 33.4 MB
    float* c  = (float*)(wsb + 884736 + 33423360);               // 33.4 MB
    unsigned short* h2 = (unsigned short*)(wsb + 884736 + 2 * (size_t)33423360); // 33.4 MB

    prep_bt<<<480, 256, 0, stream>>>(U_iou, U_f, W_iou, W_f, Btu, Btl);
    pack_weights<<<96, 256, 0, stream>>>(W_iou, W_f, U_iou, U_f, Wp, Up);

    // leaves: heap L7, 32768 nodes, 32/block
    leafgemm<<<1024, 256, 0, stream>>>(feat, Btl, b_iou, h, c, h2);

    // internal MFMA levels: 16 nodes (32 child rows)/block
    ugemm<<<1024, 256, 0, stream>>>(feat, h2, c, Btu, b_iou, b_f, h, c, h2, 63, 6); // heap L6
    ugemm<<<512,  256, 0, stream>>>(feat, h2, c, Btu, b_iou, b_f, h, c, h2, 31, 5); // heap L5
    ugemm<<<256,  256, 0, stream>>>(feat, h2, c, Btu, b_iou, b_f, h, c, h2, 15, 4); // heap L4

    // heap L3..L0 fused (VALU), one block per tree
    tree_top_kernel<<<B_TREES, 256, 0, stream>>>(feat, Wp, b_iou, Up, b_f, h, c);

    readout_kernel<<<B_TREES, 512, 0, stream>>>(
        h, lin1_w, lin1_b, lin2_w, lin2_b, lin_w, lin_b, out);
}